// Round 1
// 987.431 us; speedup vs baseline: 1.5342x; 1.5342x over previous
//
#include <hip/hip_runtime.h>

#define NBATCH 256
#define NSEQ 200
#define NPOS (NBATCH*NSEQ)
#define NW 8
#define EV_D 64
#define ITEM_D 256
#define HID 256
#define SKU_D 128
#define URL_D 128
#define LN_EPS 1e-5f
#define G 8
#define XDIM 1024   // concat [se|ce|pe|we]

// ---------- wave-level (64-lane) helpers: no block barriers ----------
__device__ __forceinline__ float wave_sum(float v) {
    #pragma unroll
    for (int o = 32; o > 0; o >>= 1) v += __shfl_xor(v, o, 64);
    return v;
}

// LN over D elements held 4-per-lane across one wave (D = 256).
__device__ __forceinline__ float4 wave_ln4(float4 v, float invD) {
    float mu = wave_sum(v.x + v.y + v.z + v.w) * invD;
    float4 d;
    d.x = v.x - mu; d.y = v.y - mu; d.z = v.z - mu; d.w = v.w - mu;
    float q = wave_sum(d.x*d.x + d.y*d.y + d.z*d.z + d.w*d.w);
    float inv = rsqrtf(q * invD + LN_EPS);
    d.x *= inv; d.y *= inv; d.z *= inv; d.w *= inv;
    return d;
}

// ---------- block-cooperative, position-batched matvecs ----------
// k-split across 4 waves; lane owns output quad [4*lane, 4*lane+3].
// Weights read ONCE per block from L2, reused for all NS sku positions.
template<int NS>
__device__ __forceinline__ void sku_batch(
    const float* __restrict__ sku_proj_W, const float* __restrict__ sku_proj_b,
    const float* __restrict__ fc1_W, const float* __restrict__ fc1_b,
    float* __restrict__ out, int pos0,
    float (&x_lds)[G][XDIM], float (&s128)[G][SKU_D],
    float4 (&red4)[4][2][64], int (&posg)[G],
    int lane, int wv)
{
    const int u4 = 4 * lane;

    // ---- sku_proj: h = se128 @ W (128x256) + b ; se = relu(ln(h)) -> x_lds[:,0:256)
    {
        float acc[NS][4];
        #pragma unroll
        for (int j = 0; j < NS; ++j) { acc[j][0]=0.f; acc[j][1]=0.f; acc[j][2]=0.f; acc[j][3]=0.f; }
        const int kb = wv * 32;                    // each wave owns 32 of 128 k's
        #pragma unroll 2
        for (int k0 = kb; k0 < kb + 32; k0 += 4) {
            float xq[NS][4];
            #pragma unroll
            for (int j = 0; j < NS; ++j) *(float4*)xq[j] = *(const float4*)&s128[j][k0];
            #pragma unroll
            for (int kk = 0; kk < 4; ++kk) {
                const float4 w4 = *(const float4*)(sku_proj_W + (size_t)(k0+kk)*HID + u4);
                #pragma unroll
                for (int j = 0; j < NS; ++j) {
                    const float xv = xq[j][kk];
                    acc[j][0] = fmaf(xv, w4.x, acc[j][0]);
                    acc[j][1] = fmaf(xv, w4.y, acc[j][1]);
                    acc[j][2] = fmaf(xv, w4.z, acc[j][2]);
                    acc[j][3] = fmaf(xv, w4.w, acc[j][3]);
                }
            }
        }
        // cross-wave reduce, 2 slots per batch; finalizing wave does bias+LN+relu
        #pragma unroll
        for (int jb = 0; jb < NS; jb += 2) {
            __syncthreads();
            red4[wv][0][lane] = *(float4*)acc[jb];
            if (jb + 1 < NS) red4[wv][1][lane] = *(float4*)acc[jb+1];
            __syncthreads();
            if (wv < 2 && jb + wv < NS) {
                const int j = jb + wv;
                const float4 a = red4[0][wv][lane], b = red4[1][wv][lane];
                const float4 c = red4[2][wv][lane], d = red4[3][wv][lane];
                const float4 bi = *(const float4*)(sku_proj_b + u4);
                float4 s;
                s.x = a.x + b.x + c.x + d.x + bi.x;
                s.y = a.y + b.y + c.y + d.y + bi.y;
                s.z = a.z + b.z + c.z + d.z + bi.z;
                s.w = a.w + b.w + c.w + d.w + bi.w;
                float4 r = wave_ln4(s, 1.f / HID);
                r.x = fmaxf(r.x, 0.f); r.y = fmaxf(r.y, 0.f);
                r.z = fmaxf(r.z, 0.f); r.w = fmaxf(r.w, 0.f);
                *(float4*)&x_lds[j][u4] = r;
            }
        }
        __syncthreads();                           // se visible to fc1 readers
    }

    // ---- fc1: item = relu(x (1024) @ W (1024x256) + b)
    {
        float acc[NS][4];
        #pragma unroll
        for (int j = 0; j < NS; ++j) { acc[j][0]=0.f; acc[j][1]=0.f; acc[j][2]=0.f; acc[j][3]=0.f; }
        const int kb = wv * 256;                   // each wave owns 256 of 1024 k's
        #pragma unroll 2
        for (int k0 = kb; k0 < kb + 256; k0 += 4) {
            float xq[NS][4];
            #pragma unroll
            for (int j = 0; j < NS; ++j) *(float4*)xq[j] = *(const float4*)&x_lds[j][k0];
            #pragma unroll
            for (int kk = 0; kk < 4; ++kk) {
                const float4 w4 = *(const float4*)(fc1_W + (size_t)(k0+kk)*ITEM_D + u4);
                #pragma unroll
                for (int j = 0; j < NS; ++j) {
                    const float xv = xq[j][kk];
                    acc[j][0] = fmaf(xv, w4.x, acc[j][0]);
                    acc[j][1] = fmaf(xv, w4.y, acc[j][1]);
                    acc[j][2] = fmaf(xv, w4.z, acc[j][2]);
                    acc[j][3] = fmaf(xv, w4.w, acc[j][3]);
                }
            }
        }
        #pragma unroll
        for (int jb = 0; jb < NS; jb += 2) {
            __syncthreads();
            red4[wv][0][lane] = *(float4*)acc[jb];
            if (jb + 1 < NS) red4[wv][1][lane] = *(float4*)acc[jb+1];
            __syncthreads();
            if (wv < 2 && jb + wv < NS) {
                const int j = jb + wv;
                const float4 a = red4[0][wv][lane], b = red4[1][wv][lane];
                const float4 c = red4[2][wv][lane], d = red4[3][wv][lane];
                const float4 bi = *(const float4*)(fc1_b + u4);
                float4 s;
                s.x = fmaxf(a.x + b.x + c.x + d.x + bi.x, 0.f);
                s.y = fmaxf(a.y + b.y + c.y + d.y + bi.y, 0.f);
                s.z = fmaxf(a.z + b.z + c.z + d.z + bi.z, 0.f);
                s.w = fmaxf(a.w + b.w + c.w + d.w + bi.w, 0.f);
                const int p = pos0 + posg[j];
                *(float4*)(out + (size_t)p * 320 + 64 + u4) = s;
            }
        }
    }
}

extern "C" __global__ __launch_bounds__(256)
void encoder_kernel(const int* __restrict__ event_type,
                    const int* __restrict__ sku_id,
                    const int* __restrict__ url_id,
                    const int* __restrict__ cat_id,
                    const int* __restrict__ price_id,
                    const int* __restrict__ word_id,
                    const float* __restrict__ event_emb,
                    const float* __restrict__ word_emb,
                    const float* __restrict__ sku_emb,
                    const float* __restrict__ sku_proj_W,
                    const float* __restrict__ sku_proj_b,
                    const float* __restrict__ cat_emb,
                    const float* __restrict__ price_emb,
                    const float* __restrict__ fc1_W,
                    const float* __restrict__ fc1_b,
                    const float* __restrict__ url_emb,
                    const float* __restrict__ url_proj_W,
                    const float* __restrict__ url_proj_b,
                    float* __restrict__ out)
{
    __shared__ __align__(16) float x_lds[G][XDIM];     // 32 KB: per-slot [se|ce|pe|we]
    __shared__ __align__(16) float s128[G][SKU_D];     // 4 KB: per-slot ln'd sku emb
    __shared__ __align__(16) float4 red4[4][2][64];    // 8 KB: cross-wave reduce
    __shared__ int einfo[G];
    __shared__ int slotofg[G];
    __shared__ int posg[G];
    __shared__ int ns_sh;

    const int t = threadIdx.x;
    const int lane = t & 63;
    const int wv = t >> 6;
    const int pos0 = blockIdx.x * G;
    const int u4 = 4 * lane;

    if (t < G) einfo[t] = event_type[pos0 + t];
    __syncthreads();
    if (t == 0) {                                     // compact sku slots
        int c = 0;
        for (int g = 0; g < G; ++g) {
            const int e = einfo[g];
            const bool sb = (e >= 2) && (e <= 4);
            slotofg[g] = sb ? c : -1;
            if (sb) posg[c++] = g;
        }
        ns_sh = c;
    }
    __syncthreads();
    const int ns = ns_sh;

    // ---- phase 1: per-position work, one wave per position (2 each), no block syncs
    for (int gi = 0; gi < 2; ++gi) {
        const int g = wv * 2 + gi;
        const int p = pos0 + g;
        const int e = einfo[g];
        float* out_pos = out + (size_t)p * 320;
        if (lane == 0) out[(size_t)NPOS * 320 + p] = (e == 0) ? 1.0f : 0.0f;

        // ev = ln(event_emb[e]) -> out[0:64), one element per lane
        {
            const float v = event_emb[e * EV_D + lane];
            const float mu = wave_sum(v) * (1.f / EV_D);
            const float d = v - mu;
            const float q = wave_sum(d * d);
            out_pos[lane] = d * rsqrtf(q * (1.f / EV_D) + LN_EPS);
        }

        const bool sku_b   = (e >= 2) && (e <= 4);
        const bool url_b   = (e == 5);
        const bool query_b = (e == 6);
        const int  slot    = slotofg[g];

        if (sku_b || query_b) {          // word layer: ln(mean_w word_emb[wid])
            const int* wid = word_id + (size_t)p * NW;
            float ax = 0.f, ay = 0.f, az = 0.f, aw = 0.f;
            #pragma unroll
            for (int w = 0; w < NW; ++w) {
                const float4 r = *(const float4*)(word_emb + (size_t)wid[w] * ITEM_D + u4);
                ax += r.x; ay += r.y; az += r.z; aw += r.w;
            }
            const float4 we4 = wave_ln4(make_float4(ax*0.125f, ay*0.125f, az*0.125f, aw*0.125f),
                                        1.f / ITEM_D);
            if (query_b) *(float4*)(out_pos + 64 + u4) = we4;
            else         *(float4*)&x_lds[slot][768 + u4] = we4;
        }

        if (sku_b) {
            {   // se128 = ln(sku_emb[sid]) -> s128 (2 elems/lane)
                const float2 v2 = *(const float2*)(sku_emb + (size_t)sku_id[p] * SKU_D + 2 * lane);
                const float mu = wave_sum(v2.x + v2.y) * (1.f / SKU_D);
                const float dx = v2.x - mu, dy = v2.y - mu;
                const float q = wave_sum(dx * dx + dy * dy);
                const float inv = rsqrtf(q * (1.f / SKU_D) + LN_EPS);
                *(float2*)&s128[slot][2 * lane] = make_float2(dx * inv, dy * inv);
            }
            {   // ce
                const float4 c4 = *(const float4*)(cat_emb + (size_t)cat_id[p] * HID + u4);
                *(float4*)&x_lds[slot][256 + u4] = wave_ln4(c4, 1.f / HID);
            }
            {   // pe
                const float4 p4 = *(const float4*)(price_emb + (size_t)price_id[p] * HID + u4);
                *(float4*)&x_lds[slot][512 + u4] = wave_ln4(p4, 1.f / HID);
            }
        } else if (url_b) {
            // ue128 = ln(url_emb[uid]), then 128x256 matvec via readlane broadcast
            const float2 v2 = *(const float2*)(url_emb + (size_t)url_id[p] * URL_D + 2 * lane);
            const float mu = wave_sum(v2.x + v2.y) * (1.f / URL_D);
            const float dx = v2.x - mu, dy = v2.y - mu;
            const float q = wave_sum(dx * dx + dy * dy);
            const float inv = rsqrtf(q * (1.f / URL_D) + LN_EPS);
            const float ux = dx * inv, uy = dy * inv;
            const float4 bi = *(const float4*)(url_proj_b + u4);
            float hx = bi.x, hy = bi.y, hz = bi.z, hw = bi.w;
            for (int ks = 0; ks < 64; ++ks) {
                const float xa = __shfl(ux, ks, 64);
                const float xb = __shfl(uy, ks, 64);
                const float* wp = url_proj_W + (size_t)(2 * ks) * HID + u4;
                const float4 wa = *(const float4*)wp;
                const float4 wb = *(const float4*)(wp + HID);
                hx = fmaf(xa, wa.x, fmaf(xb, wb.x, hx));
                hy = fmaf(xa, wa.y, fmaf(xb, wb.y, hy));
                hz = fmaf(xa, wa.z, fmaf(xb, wb.z, hz));
                hw = fmaf(xa, wa.w, fmaf(xb, wb.w, hw));
            }
            float4 u4v = wave_ln4(make_float4(hx, hy, hz, hw), 1.f / HID);
            u4v.x = fmaxf(u4v.x, 0.f); u4v.y = fmaxf(u4v.y, 0.f);
            u4v.z = fmaxf(u4v.z, 0.f); u4v.w = fmaxf(u4v.w, 0.f);
            *(float4*)(out_pos + 64 + u4) = u4v;
        } else if (!query_b) {
            // e == 0 (pad) or e == 1: agg = 0
            *(float4*)(out_pos + 64 + u4) = make_float4(0.f, 0.f, 0.f, 0.f);
        }
    }

    __syncthreads();
    if (ns == 0) return;

    switch (ns) {   // uniform across block; static accumulator indexing per NS
        case 1: sku_batch<1>(sku_proj_W, sku_proj_b, fc1_W, fc1_b, out, pos0, x_lds, s128, red4, posg, lane, wv); break;
        case 2: sku_batch<2>(sku_proj_W, sku_proj_b, fc1_W, fc1_b, out, pos0, x_lds, s128, red4, posg, lane, wv); break;
        case 3: sku_batch<3>(sku_proj_W, sku_proj_b, fc1_W, fc1_b, out, pos0, x_lds, s128, red4, posg, lane, wv); break;
        case 4: sku_batch<4>(sku_proj_W, sku_proj_b, fc1_W, fc1_b, out, pos0, x_lds, s128, red4, posg, lane, wv); break;
        case 5: sku_batch<5>(sku_proj_W, sku_proj_b, fc1_W, fc1_b, out, pos0, x_lds, s128, red4, posg, lane, wv); break;
        case 6: sku_batch<6>(sku_proj_W, sku_proj_b, fc1_W, fc1_b, out, pos0, x_lds, s128, red4, posg, lane, wv); break;
        case 7: sku_batch<7>(sku_proj_W, sku_proj_b, fc1_W, fc1_b, out, pos0, x_lds, s128, red4, posg, lane, wv); break;
        default: sku_batch<8>(sku_proj_W, sku_proj_b, fc1_W, fc1_b, out, pos0, x_lds, s128, red4, posg, lane, wv); break;
    }
}

extern "C" void kernel_launch(void* const* d_in, const int* in_sizes, int n_in,
                              void* d_out, int out_size, void* d_ws, size_t ws_size,
                              hipStream_t stream) {
    (void)in_sizes; (void)n_in; (void)out_size; (void)d_ws; (void)ws_size;
    const int*   event_type = (const int*)d_in[0];
    const int*   sku_id     = (const int*)d_in[1];
    const int*   url_id     = (const int*)d_in[2];
    const int*   cat_id     = (const int*)d_in[3];
    const int*   price_id   = (const int*)d_in[4];
    const int*   word_id    = (const int*)d_in[5];
    const float* event_emb  = (const float*)d_in[6];
    const float* word_emb   = (const float*)d_in[7];
    const float* sku_emb    = (const float*)d_in[8];
    const float* sku_proj_W = (const float*)d_in[9];
    const float* sku_proj_b = (const float*)d_in[10];
    const float* cat_emb    = (const float*)d_in[11];
    const float* price_emb  = (const float*)d_in[12];
    const float* fc1_W      = (const float*)d_in[13];
    const float* fc1_b      = (const float*)d_in[14];
    const float* url_emb    = (const float*)d_in[15];
    const float* url_proj_W = (const float*)d_in[16];
    const float* url_proj_b = (const float*)d_in[17];
    float* out = (float*)d_out;

    hipLaunchKernelGGL(encoder_kernel, dim3(NPOS / G), dim3(256), 0, stream,
                       event_type, sku_id, url_id, cat_id, price_id, word_id,
                       event_emb, word_emb, sku_emb, sku_proj_W, sku_proj_b,
                       cat_emb, price_emb, fc1_W, fc1_b,
                       url_emb, url_proj_W, url_proj_b, out);
}